// Round 1
// 1280.057 us; speedup vs baseline: 3.7737x; 3.7737x over previous
//
#include <hip/hip_runtime.h>

#define DEV __device__ __forceinline__

typedef __bf16 bf16x8 __attribute__((ext_vector_type(8)));
typedef float f32x4 __attribute__((ext_vector_type(4)));

DEV unsigned short f2bf(float f) {
    unsigned u = __builtin_bit_cast(unsigned, f);
    u += 0x7fffu + ((u >> 16) & 1u);   // round-to-nearest-even
    return (unsigned short)(u >> 16);
}

// Detect whether edge_index buffer is int64-layout (odd 32-bit words all zero,
// since node ids < 50000) or int32. Writes 1 for int64-layout, 0 for int32.
__global__ void detect_kernel(const int* __restrict__ ei, int* __restrict__ flag)
{
    if (threadIdx.x == 0 && blockIdx.x == 0) {
        int z = 1;
        for (int i = 1; i < 64; i += 2) z &= (ei[i] == 0);
        *flag = z;
    }
}

// ---------------- CSR build (once per launch; edges are layer-invariant) ----

__global__ __launch_bounds__(256) void zero_counts_kernel(int* __restrict__ counts, int N)
{
    int i = blockIdx.x * 256 + threadIdx.x;
    if (i < N) counts[i] = 0;
}

__global__ __launch_bounds__(256) void hist_kernel(
    const int* __restrict__ ei, const int* __restrict__ i64flag,
    int* __restrict__ counts, int E)
{
    int e = blockIdx.x * 256 + threadIdx.x;
    if (e >= E) return;
    int d = (*i64flag) ? ei[2 * (size_t)E + 2 * (size_t)e] : ei[(size_t)E + e];
    atomicAdd(&counts[d], 1);
}

// block-level inclusive scan; writes per-element exclusive offsets + block totals
__global__ __launch_bounds__(256) void scan1_kernel(
    const int* __restrict__ counts, int* __restrict__ offs,
    int* __restrict__ bsum, int N)
{
    __shared__ int s[256];
    int tid = threadIdx.x;
    int i = blockIdx.x * 256 + tid;
    int c = (i < N) ? counts[i] : 0;
    s[tid] = c;
    __syncthreads();
#pragma unroll
    for (int off = 1; off < 256; off <<= 1) {
        int add = (tid >= off) ? s[tid - off] : 0;
        __syncthreads();
        s[tid] += add;
        __syncthreads();
    }
    int incl = s[tid];
    if (i < N) offs[i] = incl - c;            // exclusive within block
    if (tid == 255) bsum[blockIdx.x] = incl;  // block total
}

__global__ void scan2_kernel(int* __restrict__ bsum, int nb)
{
    if (threadIdx.x == 0 && blockIdx.x == 0) {
        int run = 0;
        for (int b = 0; b < nb; ++b) { int v = bsum[b]; bsum[b] = run; run += v; }
    }
}

__global__ __launch_bounds__(256) void scan3_kernel(
    int* __restrict__ offs, const int* __restrict__ bsum,
    int* __restrict__ cursor, int N)
{
    int i = blockIdx.x * 256 + threadIdx.x;
    if (i < N) {
        int o = offs[i] + bsum[blockIdx.x];
        offs[i] = o;
        cursor[i] = o;
    }
}

__global__ __launch_bounds__(256) void scatter_kernel(
    const int* __restrict__ ei, const int* __restrict__ i64flag,
    int* __restrict__ cursor, int2* __restrict__ el, int E)
{
    int e = blockIdx.x * 256 + threadIdx.x;
    if (e >= E) return;
    int s, d;
    if (*i64flag) {
        s = ei[2 * (size_t)e];
        d = ei[2 * (size_t)E + 2 * (size_t)e];
    } else {
        s = ei[e];
        d = ei[(size_t)E + e];
    }
    int pos = atomicAdd(&cursor[d], 1);
    el[pos] = make_int2(s, e);
}

// ---------------- aggregation: t[n] = x[n] + sum_{e: dst==n} relu(x[src]+ea[e])
// One wave (64 lanes) per node, 2 dims/lane. No atomics; one write per row.
// Block 0 also zeroes the 512 stat floats for this layer.
__global__ __launch_bounds__(512) void agg_kernel(
    const float* __restrict__ x, const float* __restrict__ ea,
    const int2* __restrict__ el, const int* __restrict__ offs,
    const int* __restrict__ cnts, float* __restrict__ t,
    float* __restrict__ stats, int N)
{
    int tid = threadIdx.x;
    if (blockIdx.x == 0) stats[tid] = 0.f;   // 512 threads cover 512 floats
    int n = blockIdx.x * 8 + (tid >> 6);
    if (n >= N) return;
    int d0 = (tid & 63) * 2;
    int start = offs[n];
    int deg = cnts[n];
    float2 acc = *(const float2*)(x + (size_t)n * 128 + d0);
    int j = 0;
    for (; j + 2 <= deg; j += 2) {          // 2-way unroll for load ILP
        int2 s0 = el[start + j];
        int2 s1 = el[start + j + 1];
        float2 x0 = *(const float2*)(x + (size_t)s0.x * 128 + d0);
        float2 a0 = *(const float2*)(ea + (size_t)s0.y * 128 + d0);
        float2 x1 = *(const float2*)(x + (size_t)s1.x * 128 + d0);
        float2 a1 = *(const float2*)(ea + (size_t)s1.y * 128 + d0);
        acc.x += fmaxf(x0.x + a0.x, 0.f);
        acc.y += fmaxf(x0.y + a0.y, 0.f);
        acc.x += fmaxf(x1.x + a1.x, 0.f);
        acc.y += fmaxf(x1.y + a1.y, 0.f);
    }
    if (j < deg) {
        int2 s0 = el[start + j];
        float2 x0 = *(const float2*)(x + (size_t)s0.x * 128 + d0);
        float2 a0 = *(const float2*)(ea + (size_t)s0.y * 128 + d0);
        acc.x += fmaxf(x0.x + a0.x, 0.f);
        acc.y += fmaxf(x0.y + a0.y, 0.f);
    }
    *(float2*)(t + (size_t)n * 128 + d0) = acc;
}

// out[n][c] = sum_k in[n][k]*W[k][c] + bias[c]; f32 in/out, bf16 MFMA inside.
// Block = 64 rows x 128 cols, 4 waves. Each block stages its 64 rows to LDS
// before writing, so in-place (out == in) is safe.
__global__ __launch_bounds__(256) void gemm_kernel(
    const float* __restrict__ inp,
    const float* __restrict__ W,     // [128][128] f32, [k][c]
    const float* __restrict__ bias,  // [128] f32
    float* __restrict__ out, int N)
{
    __shared__ __attribute__((aligned(16))) unsigned short As[64][136];   // [r][k]
    __shared__ __attribute__((aligned(16))) unsigned short Ws[128][136];  // [c][k] (transposed)
    const int tid = threadIdx.x;
    const int row0 = blockIdx.x * 64;

    // stage W transposed as bf16: Ws[c][k] = W[k*128+c]
#pragma unroll
    for (int it = 0; it < 8; ++it) {
        int lin = (it * 256 + tid) * 8;
        int k = lin >> 7;
        int c = lin & 127;
        const float* wp = W + (size_t)k * 128 + c;
        float4 wa = *(const float4*)wp;
        float4 wb = *(const float4*)(wp + 4);
        Ws[c + 0][k] = f2bf(wa.x); Ws[c + 1][k] = f2bf(wa.y);
        Ws[c + 2][k] = f2bf(wa.z); Ws[c + 3][k] = f2bf(wa.w);
        Ws[c + 4][k] = f2bf(wb.x); Ws[c + 5][k] = f2bf(wb.y);
        Ws[c + 6][k] = f2bf(wb.z); Ws[c + 7][k] = f2bf(wb.w);
    }
    // stage A tile as bf16 (zero-pad tail rows)
#pragma unroll
    for (int it = 0; it < 8; ++it) {
        int lin = (it * 256 + tid) * 4;
        int r = lin >> 7;
        int c = lin & 127;
        int row = row0 + r;
        if (row < N) {
            float4 v = *(const float4*)(inp + (size_t)row * 128 + c);
            As[r][c + 0] = f2bf(v.x); As[r][c + 1] = f2bf(v.y);
            As[r][c + 2] = f2bf(v.z); As[r][c + 3] = f2bf(v.w);
        } else {
            As[r][c + 0] = 0; As[r][c + 1] = 0; As[r][c + 2] = 0; As[r][c + 3] = 0;
        }
    }
    __syncthreads();

    const int wave = tid >> 6;
    const int lane = tid & 63;
    const int quad = lane >> 4;
    const int m16  = lane & 15;

    // A fragments: A[m=lane&15][k=quad*8+j], 8 contiguous bf16 -> ds_read_b128
    bf16x8 af[4];
#pragma unroll
    for (int kk = 0; kk < 4; ++kk)
        af[kk] = *reinterpret_cast<const bf16x8*>(&As[wave * 16 + m16][kk * 32 + quad * 8]);

#pragma unroll
    for (int ct = 0; ct < 8; ++ct) {
        f32x4 acc = {0.f, 0.f, 0.f, 0.f};
#pragma unroll
        for (int kk = 0; kk < 4; ++kk) {
            // B fragment: B[k=quad*8+j][n=lane&15] = Ws[n][k], contiguous in k
            bf16x8 bf = *reinterpret_cast<const bf16x8*>(&Ws[ct * 16 + m16][kk * 32 + quad * 8]);
            acc = __builtin_amdgcn_mfma_f32_16x16x32_bf16(af[kk], bf, acc, 0, 0, 0);
        }
        int col = ct * 16 + m16;
        float bb = bias[col];
#pragma unroll
        for (int r = 0; r < 4; ++r) {
            int row = row0 + wave * 16 + quad * 4 + r;  // C/D: row = quad*4+reg, col = lane&15
            if (row < N) out[(size_t)row * 128 + col] = acc[r] + bb;
        }
    }
}

// column sums / sums-of-squares over N rows
__global__ __launch_bounds__(256) void stats_kernel(
    const float* __restrict__ t, float* __restrict__ sum, float* __restrict__ sq, int N)
{
    __shared__ float ss[128], qq[128];
    int tid = threadIdx.x;
    if (tid < 128) { ss[tid] = 0.f; qq[tid] = 0.f; }
    __syncthreads();
    int g = blockIdx.x * 256 + tid;
    int c4 = (g & 31) * 4;
    int r = g >> 5;
    int rstride = (gridDim.x * 256) >> 5;
    float s0 = 0, s1 = 0, s2 = 0, s3 = 0, q0 = 0, q1 = 0, q2 = 0, q3 = 0;
    for (; r < N; r += rstride) {
        float4 v = *(const float4*)(t + (size_t)r * 128 + c4);
        s0 += v.x; q0 += v.x * v.x;
        s1 += v.y; q1 += v.y * v.y;
        s2 += v.z; q2 += v.z * v.z;
        s3 += v.w; q3 += v.w * v.w;
    }
    atomicAdd(&ss[c4 + 0], s0); atomicAdd(&qq[c4 + 0], q0);
    atomicAdd(&ss[c4 + 1], s1); atomicAdd(&qq[c4 + 1], q1);
    atomicAdd(&ss[c4 + 2], s2); atomicAdd(&qq[c4 + 2], q2);
    atomicAdd(&ss[c4 + 3], s3); atomicAdd(&qq[c4 + 3], q3);
    __syncthreads();
    if (tid < 128) { atomicAdd(&sum[tid], ss[tid]); atomicAdd(&sq[tid], qq[tid]); }
}

// out = [relu?] (gamma * (t - mean) * rsqrt(var + eps) + beta), f32 out
__global__ __launch_bounds__(256) void bn_kernel(
    const float* __restrict__ t, const float* __restrict__ sum, const float* __restrict__ sq,
    const float* __restrict__ gamma, const float* __restrict__ beta,
    float* __restrict__ out, int N, int do_relu, int nv4)
{
    __shared__ float sc[128], sh[128];
    int tid = threadIdx.x;
    if (tid < 128) {
        float inv = 1.f / (float)N;
        float m = sum[tid] * inv;
        float v = sq[tid] * inv - m * m;
        v = fmaxf(v, 0.f);
        float rs = rsqrtf(v + 1e-5f);
        float gr = gamma[tid] * rs;
        sc[tid] = gr;
        sh[tid] = beta[tid] - m * gr;
    }
    __syncthreads();
    int g = blockIdx.x * 256 + tid;
    if (g < nv4) {
        int c = (g & 31) * 4;
        float4 v = *(const float4*)(t + (size_t)g * 4);
        float4 o;
        o.x = v.x * sc[c + 0] + sh[c + 0];
        o.y = v.y * sc[c + 1] + sh[c + 1];
        o.z = v.z * sc[c + 2] + sh[c + 2];
        o.w = v.w * sc[c + 3] + sh[c + 3];
        if (do_relu) {
            o.x = fmaxf(o.x, 0.f); o.y = fmaxf(o.y, 0.f);
            o.z = fmaxf(o.z, 0.f); o.w = fmaxf(o.w, 0.f);
        }
        *(float4*)(out + (size_t)g * 4) = o;
    }
}

extern "C" void kernel_launch(void* const* d_in, const int* in_sizes, int n_in,
                              void* d_out, int out_size, void* d_ws, size_t ws_size,
                              hipStream_t stream)
{
    const float* x  = (const float*)d_in[0];
    const int* ei   = (const int*)d_in[1];
    const float* ea = (const float*)d_in[2];
    // d_in[3] = batch (unused)
    const float* W1 = (const float*)d_in[4];
    const float* b1 = (const float*)d_in[5];
    const float* gm = (const float*)d_in[6];
    const float* bm = (const float*)d_in[7];
    const float* W2 = (const float*)d_in[8];
    const float* b2 = (const float*)d_in[9];
    const float* go = (const float*)d_in[10];
    const float* bo = (const float*)d_in[11];
    float* out = (float*)d_out;

    const int N = in_sizes[0] / 128;   // 50000
    const int E = in_sizes[2] / 128;   // 800000

    char* w = (char*)d_ws;
    float* t    = (float*)w;   w += (size_t)N * 128 * 4;   // aggr & gemm buf (in-place)
    float* xbuf = (float*)w;   w += (size_t)N * 128 * 4;   // inter-layer x
    float* hbuf = (float*)w;   w += (size_t)N * 128 * 4;   // post-BN1 activations
    float* stats = (float*)w;  w += 512 * 4;
    int* i64flag = (int*)w;    w += 16;
    int* counts  = (int*)w;    w += (size_t)N * 4;
    int* offs    = (int*)w;    w += (size_t)N * 4;
    int* cursor  = (int*)w;    w += (size_t)N * 4;
    int* bsum    = (int*)w;    w += 256 * 4;
    int2* el     = (int2*)w;   w += (size_t)E * 8;

    const int nv4 = N * 32;
    const int gElem = (nv4 + 255) / 256;
    const int gGemm = (N + 63) / 64;
    const int gEdge = (E + 255) / 256;
    const int nb    = (N + 255) / 256;
    const int gAgg  = (N + 7) / 8;

    // ---- CSR build (edge structure is identical across layers) ----
    detect_kernel<<<1, 64, 0, stream>>>(ei, i64flag);
    zero_counts_kernel<<<nb, 256, 0, stream>>>(counts, N);
    hist_kernel<<<gEdge, 256, 0, stream>>>(ei, i64flag, counts, E);
    scan1_kernel<<<nb, 256, 0, stream>>>(counts, offs, bsum, N);
    scan2_kernel<<<1, 64, 0, stream>>>(bsum, nb);
    scan3_kernel<<<nb, 256, 0, stream>>>(offs, bsum, cursor, N);
    scatter_kernel<<<gEdge, 256, 0, stream>>>(ei, i64flag, cursor, el, E);

    for (int i = 0; i < 3; ++i) {
        const float* xin = (i == 0) ? x : xbuf;
        float* xout = (i == 2) ? out : xbuf;

        agg_kernel<<<gAgg, 512, 0, stream>>>(xin, ea, el, offs, counts, t, stats, N);
        gemm_kernel<<<gGemm, 256, 0, stream>>>(t, W1 + (size_t)i * 16384, b1 + i * 128, t, N);
        stats_kernel<<<256, 256, 0, stream>>>(t, stats, stats + 128, N);
        bn_kernel<<<gElem, 256, 0, stream>>>(t, stats, stats + 128, gm + i * 128, bm + i * 128,
                                             hbuf, N, 1, nv4);
        gemm_kernel<<<gGemm, 256, 0, stream>>>(hbuf, W2 + (size_t)i * 16384, b2 + i * 128, t, N);
        stats_kernel<<<256, 256, 0, stream>>>(t, stats + 256, stats + 384, N);
        bn_kernel<<<gElem, 256, 0, stream>>>(t, stats + 256, stats + 384, go + i * 128, bo + i * 128,
                                             xout, N, (i < 2) ? 1 : 0, nv4);
    }
}

// Round 2
// 1193.584 us; speedup vs baseline: 4.0471x; 1.0724x over previous
//
#include <hip/hip_runtime.h>

#define DEV __device__ __forceinline__

typedef __bf16 bf16x8 __attribute__((ext_vector_type(8)));
typedef float f32x4 __attribute__((ext_vector_type(4)));
typedef float f32x2 __attribute__((ext_vector_type(2)));

DEV unsigned short f2bf(float f) {
    unsigned u = __builtin_bit_cast(unsigned, f);
    u += 0x7fffu + ((u >> 16) & 1u);   // round-to-nearest-even
    return (unsigned short)(u >> 16);
}

// Detect whether edge_index buffer is int64-layout (odd 32-bit words all zero,
// since node ids < 50000) or int32. Parallel: 32 lanes check one word each.
__global__ void detect_kernel(const int* __restrict__ ei, int* __restrict__ flag)
{
    int t = threadIdx.x;                      // 64 threads
    int v = (t < 32) ? ei[2 * t + 1] : 0;
    unsigned long long b = __ballot(v == 0);
    if (t == 0) *flag = (b == ~0ull) ? 1 : 0;
}

// zero counts[N] and stats[1536] (6 slots x 256 floats)
__global__ __launch_bounds__(256) void zero_kernel(
    int* __restrict__ counts, float* __restrict__ stats, int N)
{
    int i = blockIdx.x * 256 + threadIdx.x;
    if (i < N) counts[i] = 0;
    if (i < 1536) stats[i] = 0.f;
}

__global__ __launch_bounds__(256) void hist_kernel(
    const int* __restrict__ ei, const int* __restrict__ i64flag,
    int* __restrict__ counts, int E)
{
    int e = blockIdx.x * 256 + threadIdx.x;
    if (e >= E) return;
    int d = (*i64flag) ? ei[2 * (size_t)E + 2 * (size_t)e] : ei[(size_t)E + e];
    atomicAdd(&counts[d], 1);
}

// block-level inclusive scan; writes per-element exclusive offsets + block totals
__global__ __launch_bounds__(256) void scan1_kernel(
    const int* __restrict__ counts, int* __restrict__ offs,
    int* __restrict__ bsum, int N)
{
    __shared__ int s[256];
    int tid = threadIdx.x;
    int i = blockIdx.x * 256 + tid;
    int c = (i < N) ? counts[i] : 0;
    s[tid] = c;
    __syncthreads();
#pragma unroll
    for (int off = 1; off < 256; off <<= 1) {
        int add = (tid >= off) ? s[tid - off] : 0;
        __syncthreads();
        s[tid] += add;
        __syncthreads();
    }
    int incl = s[tid];
    if (i < N) offs[i] = incl - c;            // exclusive within block
    if (tid == 255) bsum[blockIdx.x] = incl;  // block total
}

// parallel exclusive scan of block sums (nb <= 256 for N = 50000)
__global__ __launch_bounds__(256) void scan2_kernel(int* __restrict__ bsum, int nb)
{
    __shared__ int s[256];
    int tid = threadIdx.x;
    int v = (tid < nb) ? bsum[tid] : 0;
    s[tid] = v;
    __syncthreads();
#pragma unroll
    for (int off = 1; off < 256; off <<= 1) {
        int add = (tid >= off) ? s[tid - off] : 0;
        __syncthreads();
        s[tid] += add;
        __syncthreads();
    }
    if (tid < nb) bsum[tid] = s[tid] - v;     // exclusive
}

__global__ __launch_bounds__(256) void scan3_kernel(
    int* __restrict__ offs, const int* __restrict__ bsum,
    int* __restrict__ cursor, int N)
{
    int i = blockIdx.x * 256 + threadIdx.x;
    if (i < N) {
        int o = offs[i] + bsum[blockIdx.x];
        offs[i] = o;
        cursor[i] = o;
    }
}

__global__ __launch_bounds__(256) void scatter_kernel(
    const int* __restrict__ ei, const int* __restrict__ i64flag,
    int* __restrict__ cursor, int2* __restrict__ el, int E)
{
    int e = blockIdx.x * 256 + threadIdx.x;
    if (e >= E) return;
    int s, d;
    if (*i64flag) {
        s = ei[2 * (size_t)e];
        d = ei[2 * (size_t)E + 2 * (size_t)e];
    } else {
        s = ei[e];
        d = ei[(size_t)E + e];
    }
    int pos = atomicAdd(&cursor[d], 1);
    el[pos] = make_int2(s, e);
}

// ---------------- aggregation ----------------
// t[n] = xbn[n] + sum_{e: dst==n} relu(xbn[src] + ea[e])
// where xbn = AFFINE ? relu(x*sc + sh) : x  (outer BN of previous layer folded in).
// One wave per node, 2 dims/lane. No atomics; one write per row.
template<bool AFFINE>
__global__ __launch_bounds__(512) void agg_kernel(
    const float* __restrict__ x, const float* __restrict__ ea,
    const int2* __restrict__ el, const int* __restrict__ offs,
    const int* __restrict__ cnts,
    const float* __restrict__ statsIn, const float* __restrict__ gamma,
    const float* __restrict__ beta,
    float* __restrict__ t, int N)
{
    __shared__ float sc[128], sh[128];
    int tid = threadIdx.x;
    if (AFFINE) {
        if (tid < 128) {
            float inv = 1.f / (float)N;
            float m = statsIn[tid] * inv;
            float v = statsIn[128 + tid] * inv - m * m;
            v = fmaxf(v, 0.f);
            float rs = rsqrtf(v + 1e-5f);
            float gr = gamma[tid] * rs;
            sc[tid] = gr;
            sh[tid] = beta[tid] - m * gr;
        }
        __syncthreads();
    }
    int n = blockIdx.x * 8 + (tid >> 6);
    if (n >= N) return;
    int d0 = (tid & 63) * 2;
    float sc0 = 1.f, sc1 = 1.f, sh0 = 0.f, sh1 = 0.f;
    if (AFFINE) { sc0 = sc[d0]; sc1 = sc[d0 + 1]; sh0 = sh[d0]; sh1 = sh[d0 + 1]; }

    int start = offs[n];
    int deg = cnts[n];

    f32x2 cv = *(const f32x2*)(x + (size_t)n * 128 + d0);
    float acc0 = cv.x, acc1 = cv.y;
    if (AFFINE) {
        acc0 = fmaxf(fmaf(acc0, sc0, sh0), 0.f);
        acc1 = fmaxf(fmaf(acc1, sc1, sh1), 0.f);
    }

#define EDGE_TERM(SE) { \
    f32x2 gx = *(const f32x2*)(x + (size_t)(SE).x * 128 + d0); \
    f32x2 av = __builtin_nontemporal_load((const f32x2*)(ea + (size_t)(SE).y * 128 + d0)); \
    float g0 = gx.x, g1 = gx.y; \
    if (AFFINE) { g0 = fmaxf(fmaf(g0, sc0, sh0), 0.f); g1 = fmaxf(fmaf(g1, sc1, sh1), 0.f); } \
    acc0 += fmaxf(g0 + av.x, 0.f); acc1 += fmaxf(g1 + av.y, 0.f); }

    int j = 0;
    for (; j + 4 <= deg; j += 4) {
        int2 e0 = el[start + j + 0];
        int2 e1 = el[start + j + 1];
        int2 e2 = el[start + j + 2];
        int2 e3 = el[start + j + 3];
        EDGE_TERM(e0); EDGE_TERM(e1); EDGE_TERM(e2); EDGE_TERM(e3);
    }
    for (; j < deg; ++j) {
        int2 e0 = el[start + j];
        EDGE_TERM(e0);
    }
#undef EDGE_TERM

    f32x2 o; o.x = acc0; o.y = acc1;
    *(f32x2*)(t + (size_t)n * 128 + d0) = o;
}

// ---------------- GEMM with fused BN-affine on A (optional) + fused col stats
// out[n][c] = sum_k a[n][k]*W[k][c] + bias[c], a = BNA ? relu(inp*sc+sh) : inp.
// Also accumulates column sum/sumsq of out into statsOut[0..127]/[128..255].
template<bool BNA>
__global__ __launch_bounds__(256) void gemm_kernel(
    const float* __restrict__ inp,
    const float* __restrict__ W,      // [128][128] f32, [k][c]
    const float* __restrict__ bias,   // [128] f32
    const float* __restrict__ statsIn,
    const float* __restrict__ gA, const float* __restrict__ bA,
    float* __restrict__ out, float* __restrict__ statsOut, int N)
{
    __shared__ __attribute__((aligned(16))) unsigned short As[64][136];   // [r][k]
    __shared__ __attribute__((aligned(16))) unsigned short Ws[128][136];  // [c][k]
    __shared__ float u0[128], u1[128];  // BNA: sc/sh during staging; then cs/cq
    const int tid = threadIdx.x;
    const int row0 = blockIdx.x * 64;

    if (BNA) {
        if (tid < 128) {
            float inv = 1.f / (float)N;
            float m = statsIn[tid] * inv;
            float v = statsIn[128 + tid] * inv - m * m;
            v = fmaxf(v, 0.f);
            float rs = rsqrtf(v + 1e-5f);
            float gr = gA[tid] * rs;
            u0[tid] = gr;
            u1[tid] = bA[tid] - m * gr;
        }
        __syncthreads();
    }

    // stage W transposed as bf16: Ws[c][k] = W[k*128+c]
#pragma unroll
    for (int it = 0; it < 8; ++it) {
        int lin = (it * 256 + tid) * 8;
        int k = lin >> 7;
        int c = lin & 127;
        const float* wp = W + (size_t)k * 128 + c;
        float4 wa = *(const float4*)wp;
        float4 wb = *(const float4*)(wp + 4);
        Ws[c + 0][k] = f2bf(wa.x); Ws[c + 1][k] = f2bf(wa.y);
        Ws[c + 2][k] = f2bf(wa.z); Ws[c + 3][k] = f2bf(wa.w);
        Ws[c + 4][k] = f2bf(wb.x); Ws[c + 5][k] = f2bf(wb.y);
        Ws[c + 6][k] = f2bf(wb.z); Ws[c + 7][k] = f2bf(wb.w);
    }
    // stage A tile as bf16 (affine+relu if BNA; zero-pad tail rows)
#pragma unroll
    for (int it = 0; it < 8; ++it) {
        int lin = (it * 256 + tid) * 4;
        int r = lin >> 7;
        int c = lin & 127;
        int row = row0 + r;
        if (row < N) {
            float4 v = *(const float4*)(inp + (size_t)row * 128 + c);
            if (BNA) {
                v.x = fmaxf(fmaf(v.x, u0[c + 0], u1[c + 0]), 0.f);
                v.y = fmaxf(fmaf(v.y, u0[c + 1], u1[c + 1]), 0.f);
                v.z = fmaxf(fmaf(v.z, u0[c + 2], u1[c + 2]), 0.f);
                v.w = fmaxf(fmaf(v.w, u0[c + 3], u1[c + 3]), 0.f);
            }
            As[r][c + 0] = f2bf(v.x); As[r][c + 1] = f2bf(v.y);
            As[r][c + 2] = f2bf(v.z); As[r][c + 3] = f2bf(v.w);
        } else {
            As[r][c + 0] = 0; As[r][c + 1] = 0; As[r][c + 2] = 0; As[r][c + 3] = 0;
        }
    }
    __syncthreads();
    // repurpose u0/u1 as column sum / sumsq accumulators
    if (tid < 128) { u0[tid] = 0.f; u1[tid] = 0.f; }
    __syncthreads();

    const int wave = tid >> 6;
    const int lane = tid & 63;
    const int quad = lane >> 4;
    const int m16  = lane & 15;

    // A fragments: A[m=lane&15][k=quad*8+j], 8 contiguous bf16 -> ds_read_b128
    bf16x8 af[4];
#pragma unroll
    for (int kk = 0; kk < 4; ++kk)
        af[kk] = *reinterpret_cast<const bf16x8*>(&As[wave * 16 + m16][kk * 32 + quad * 8]);

#pragma unroll
    for (int ct = 0; ct < 8; ++ct) {
        f32x4 acc = {0.f, 0.f, 0.f, 0.f};
#pragma unroll
        for (int kk = 0; kk < 4; ++kk) {
            bf16x8 bf = *reinterpret_cast<const bf16x8*>(&Ws[ct * 16 + m16][kk * 32 + quad * 8]);
            acc = __builtin_amdgcn_mfma_f32_16x16x32_bf16(af[kk], bf, acc, 0, 0, 0);
        }
        int col = ct * 16 + m16;
        float bb = bias[col];
        float s_part = 0.f, q_part = 0.f;
#pragma unroll
        for (int r = 0; r < 4; ++r) {
            int row = row0 + wave * 16 + quad * 4 + r;  // C/D: row = quad*4+reg, col = lane&15
            if (row < N) {
                float val = acc[r] + bb;
                out[(size_t)row * 128 + col] = val;
                s_part += val;
                q_part += val * val;
            }
        }
        // reduce over the 4 quad-groups that share this column (lanes ^16, ^32)
        s_part += __shfl_xor(s_part, 16); q_part += __shfl_xor(q_part, 16);
        s_part += __shfl_xor(s_part, 32); q_part += __shfl_xor(q_part, 32);
        if (lane < 16) {
            atomicAdd(&u0[col], s_part);
            atomicAdd(&u1[col], q_part);
        }
    }
    __syncthreads();
    if (tid < 128) {
        atomicAdd(&statsOut[tid],       u0[tid]);
        atomicAdd(&statsOut[128 + tid], u1[tid]);
    }
}

// out = [relu?] (gamma * (t - mean) * rsqrt(var + eps) + beta), f32 out
// (used only for the final layer's output)
__global__ __launch_bounds__(256) void bn_kernel(
    const float* __restrict__ t, const float* __restrict__ sum, const float* __restrict__ sq,
    const float* __restrict__ gamma, const float* __restrict__ beta,
    float* __restrict__ out, int N, int do_relu, int nv4)
{
    __shared__ float sc[128], sh[128];
    int tid = threadIdx.x;
    if (tid < 128) {
        float inv = 1.f / (float)N;
        float m = sum[tid] * inv;
        float v = sq[tid] * inv - m * m;
        v = fmaxf(v, 0.f);
        float rs = rsqrtf(v + 1e-5f);
        float gr = gamma[tid] * rs;
        sc[tid] = gr;
        sh[tid] = beta[tid] - m * gr;
    }
    __syncthreads();
    int g = blockIdx.x * 256 + tid;
    if (g < nv4) {
        int c = (g & 31) * 4;
        float4 v = *(const float4*)(t + (size_t)g * 4);
        float4 o;
        o.x = v.x * sc[c + 0] + sh[c + 0];
        o.y = v.y * sc[c + 1] + sh[c + 1];
        o.z = v.z * sc[c + 2] + sh[c + 2];
        o.w = v.w * sc[c + 3] + sh[c + 3];
        if (do_relu) {
            o.x = fmaxf(o.x, 0.f); o.y = fmaxf(o.y, 0.f);
            o.z = fmaxf(o.z, 0.f); o.w = fmaxf(o.w, 0.f);
        }
        *(float4*)(out + (size_t)g * 4) = o;
    }
}

extern "C" void kernel_launch(void* const* d_in, const int* in_sizes, int n_in,
                              void* d_out, int out_size, void* d_ws, size_t ws_size,
                              hipStream_t stream)
{
    const float* x  = (const float*)d_in[0];
    const int* ei   = (const int*)d_in[1];
    const float* ea = (const float*)d_in[2];
    // d_in[3] = batch (unused)
    const float* W1 = (const float*)d_in[4];
    const float* b1 = (const float*)d_in[5];
    const float* gm = (const float*)d_in[6];
    const float* bm = (const float*)d_in[7];
    const float* W2 = (const float*)d_in[8];
    const float* b2 = (const float*)d_in[9];
    const float* go = (const float*)d_in[10];
    const float* bo = (const float*)d_in[11];
    float* out = (float*)d_out;

    const int N = in_sizes[0] / 128;   // 50000
    const int E = in_sizes[2] / 128;   // 800000

    char* w = (char*)d_ws;
    float* t1   = (float*)w;   w += (size_t)N * 128 * 4;   // aggr output
    float* t2   = (float*)w;   w += (size_t)N * 128 * 4;   // gemm1 output (pre-BN1)
    float* t3   = (float*)w;   w += (size_t)N * 128 * 4;   // gemm2 output (pre-BN2)
    float* stats = (float*)w;  w += 1536 * 4;              // 6 slots x (sum[128], sq[128])
    int* i64flag = (int*)w;    w += 16;
    int* counts  = (int*)w;    w += (size_t)N * 4;
    int* offs    = (int*)w;    w += (size_t)N * 4;
    int* cursor  = (int*)w;    w += (size_t)N * 4;
    int* bsum    = (int*)w;    w += 256 * 4;
    int2* el     = (int2*)w;   w += (size_t)E * 8;

    const int nv4 = N * 32;
    const int gElem = (nv4 + 255) / 256;
    const int gGemm = (N + 63) / 64;
    const int gEdge = (E + 255) / 256;
    const int nb    = (N + 255) / 256;
    const int gAgg  = (N + 7) / 8;

    // ---- CSR build (edge structure is identical across layers) ----
    detect_kernel<<<1, 64, 0, stream>>>(ei, i64flag);
    zero_kernel<<<nb, 256, 0, stream>>>(counts, stats, N);
    hist_kernel<<<gEdge, 256, 0, stream>>>(ei, i64flag, counts, E);
    scan1_kernel<<<nb, 256, 0, stream>>>(counts, offs, bsum, N);
    scan2_kernel<<<1, 256, 0, stream>>>(bsum, nb);
    scan3_kernel<<<nb, 256, 0, stream>>>(offs, bsum, cursor, N);
    scatter_kernel<<<gEdge, 256, 0, stream>>>(ei, i64flag, cursor, el, E);

    for (int i = 0; i < 3; ++i) {
        float* sMlp = stats + (size_t)i * 512;        // gemm1 output stats
        float* sOut = stats + (size_t)i * 512 + 256;  // gemm2 output stats

        if (i == 0) {
            agg_kernel<false><<<gAgg, 512, 0, stream>>>(
                x, ea, el, offs, counts, nullptr, nullptr, nullptr, t1, N);
        } else {
            float* sPrev = stats + (size_t)(i - 1) * 512 + 256;
            agg_kernel<true><<<gAgg, 512, 0, stream>>>(
                t3, ea, el, offs, counts, sPrev, go + (i - 1) * 128, bo + (i - 1) * 128, t1, N);
        }
        gemm_kernel<false><<<gGemm, 256, 0, stream>>>(
            t1, W1 + (size_t)i * 16384, b1 + i * 128,
            nullptr, nullptr, nullptr, t2, sMlp, N);
        gemm_kernel<true><<<gGemm, 256, 0, stream>>>(
            t2, W2 + (size_t)i * 16384, b2 + i * 128,
            sMlp, gm + i * 128, bm + i * 128, t3, sOut, N);
    }
    // final outer BN (no relu) -> out
    bn_kernel<<<gElem, 256, 0, stream>>>(t3, stats + 2 * 512 + 256, stats + 2 * 512 + 384,
                                         go + 256, bo + 256, out, N, 0, nv4);
}